// Round 9
// baseline (532.988 us; speedup 1.0000x reference)
//
#include <hip/hip_runtime.h>

#define N_NODES  50000
#define N_EDGES  1200000
#define N_GRAPHS 1024
#define N_FEAT   9
#define EMB      64
#define SCAN_NB  ((N_NODES + 255) / 256)   // 196 blocks
#define KSPLIT   16                        // histogram split factor
#define FB       4                         // feature blocks (16 floats each)
#define NBPF     ((N_NODES + 3) / 4)       // node-blocks per feature block

// ---------------------------------------------------------------------------
// CSR build. g = dinv*h prescale makes edge weights unnecessary:
//   agg_i = dinv_i * ( g_i + sum_{e:(src->i)} g[src_e] )
// CSR stores only the 4-byte src index.
// g for layers 0..2 is stored in 4 column SLABS g[fb][node][16] (3.2 MB each)
// so each aggregation phase's gather working set fits a 4 MiB XCD L2.
// ---------------------------------------------------------------------------

// rank[e] = arrival index of edge e within its (k, dst) bucket
__global__ __launch_bounds__(256) void rank_kernel(const int* __restrict__ dst,
                                                   int* __restrict__ cntk,
                                                   int* __restrict__ rank, int ne) {
    int i = blockIdx.x * blockDim.x + threadIdx.x;
    if (i < ne) {
        int k = i & (KSPLIT - 1);
        rank[i] = atomicAdd(&cntk[k * N_NODES + dst[i]], 1);
    }
}

// per-node: exclusive prefix over k (in-place cntk -> offsets), cnt totals,
// dinv, layer-0 prescale g0 = dinv*x, per-block sums, + fused graph-boundary
__global__ __launch_bounds__(256) void merge_kernel(int* __restrict__ cntk,
                                                    const float* __restrict__ x,
                                                    const int* __restrict__ batch,
                                                    int* __restrict__ cnt,
                                                    int* __restrict__ bsum,
                                                    float* __restrict__ dinv,
                                                    float* __restrict__ g0,
                                                    int* __restrict__ gstart, int n) {
    __shared__ int sw[4];
    int t = threadIdx.x;
    int i = blockIdx.x * 256 + t;
    int total = 0;
    if (i < n) {
        int s = 0;
#pragma unroll
        for (int k = 0; k < KSPLIT; ++k) {
            int c = cntk[k * N_NODES + i];
            cntk[k * N_NODES + i] = s;     // exclusive offset for (k, i)
            s += c;
        }
        total = s;
        cnt[i] = s;
        float d = (float)s + 1.0f;         // degree with self-loop
        float dv = rsqrtf(d);
        dinv[i] = dv;
#pragma unroll
        for (int f = 0; f < N_FEAT; ++f)
            g0[i * N_FEAT + f] = dv * x[i * N_FEAT + f];
        int b = batch[i];
        if (i == 0 || batch[i - 1] != b) gstart[b] = i;
        if (i == 0) gstart[N_GRAPHS] = n;
    }
    int r = total;
#pragma unroll
    for (int off = 32; off; off >>= 1) r += __shfl_down(r, off, 64);
    if ((t & 63) == 0) sw[t >> 6] = r;
    __syncthreads();
    if (t == 0) bsum[blockIdx.x] = sw[0] + sw[1] + sw[2] + sw[3];
}

// block prefix from bsum + block-local exclusive scan -> rowp
__global__ __launch_bounds__(256) void scanfill_kernel(const int* __restrict__ cnt,
                                                       const int* __restrict__ bsum,
                                                       int* __restrict__ rowp, int n) {
    __shared__ int sw[4];
    __shared__ int s_off;
    __shared__ int lds[256];
    int t = threadIdx.x;
    int p = (t < blockIdx.x) ? bsum[t] : 0;
#pragma unroll
    for (int off = 32; off; off >>= 1) p += __shfl_down(p, off, 64);
    if ((t & 63) == 0) sw[t >> 6] = p;
    __syncthreads();
    if (t == 0) s_off = sw[0] + sw[1] + sw[2] + sw[3];
    int i = blockIdx.x * 256 + t;
    int v = (i < n) ? cnt[i] : 0;
    lds[t] = v;
    __syncthreads();
    for (int off = 1; off < 256; off <<= 1) {
        int u = (t >= off) ? lds[t - off] : 0;
        __syncthreads();
        lds[t] += u;
        __syncthreads();
    }
    if (i < n) rowp[i] = s_off + lds[t] - v;   // exclusive
    if (i == 0) rowp[n] = N_EDGES;
}

// pure scatter: csr[rowp[d] + offk[k][d] + rank[e]] = src[e]
__global__ __launch_bounds__(256) void fill2_kernel(const int* __restrict__ src,
                                                    const int* __restrict__ dst,
                                                    const int* __restrict__ rank,
                                                    const int* __restrict__ rowp,
                                                    const int* __restrict__ cntk,
                                                    int* __restrict__ csr, int ne) {
    int i = blockIdx.x * blockDim.x + threadIdx.x;
    if (i >= ne) return;
    int d = dst[i];
    int k = i & (KSPLIT - 1);
    csr[rowp[d] + cntk[k * N_NODES + d] + rank[i]] = src[i];
}

// ---------------------------------------------------------------------------
// Layer-0 aggregation (9-dim): a[i] = dinv_i * (g0[i] + sum_e g0[src_e])
// g0 is 1.8 MB -> already L2-resident; keep row-major.
// ---------------------------------------------------------------------------

__global__ __launch_bounds__(256) void agg9_kernel(const float* __restrict__ g0,
                                                   const int* __restrict__ csr,
                                                   const int* __restrict__ rowp,
                                                   const float* __restrict__ dinv,
                                                   float* __restrict__ a, int n) {
    int wave = blockIdx.x * (blockDim.x >> 6) + (threadIdx.x >> 6);
    int lane = threadIdx.x & 63;
    if (wave >= n) return;
    int beg = rowp[wave], end = rowp[wave + 1];
    int slot = lane / 9;          // 0..7 (lane 63 -> slot 7, masked off)
    int f    = lane - slot * 9;   // 0..8
    float p = 0.0f;
    int e = beg;
    for (; e + 7 <= end; e += 7) {
        if (slot < 7) {
            int s = csr[e + slot];
            p += g0[s * N_FEAT + f];
        }
    }
    for (; e < end; ++e) {
        if (lane < N_FEAT) {
            int s = csr[e];
            p += g0[s * N_FEAT + lane];
        }
    }
    float tot = p;
#pragma unroll
    for (int s = 1; s < 7; ++s) {
        float t = __shfl(p, 9 * s + lane, 64);
        if (lane < N_FEAT) tot += t;
    }
    if (lane < N_FEAT)
        a[wave * N_FEAT + lane] = dinv[wave] * (tot + g0[wave * N_FEAT + lane]);
}

// ---------------------------------------------------------------------------
// 64-dim aggregation, feature-blocked for L2 residency:
//   phase fb gathers only slab g[fb][*][16] (3.2 MB, fits XCD L2).
// fb-major blockIdx => co-resident blocks share one slab.
// wave per node; lane = slot*16 + f (4 edge slots x 16 feats); 8 edges/iter.
// ---------------------------------------------------------------------------

__global__ __launch_bounds__(256) void agg64_fb_kernel(const float* __restrict__ g,
                                                       const int* __restrict__ csr,
                                                       const int* __restrict__ rowp,
                                                       const float* __restrict__ dinv,
                                                       float* __restrict__ a, int n) {
    int fb = blockIdx.x / NBPF;
    int nb = blockIdx.x - fb * NBPF;
    int node = nb * 4 + (threadIdx.x >> 6);
    if (node >= n) return;
    int lane = threadIdx.x & 63;
    int slot = lane >> 4;         // 0..3
    int f    = lane & 15;         // 0..15
    const float* gs = g + (size_t)fb * N_NODES * 16;   // this phase's slab
    int beg = rowp[node], end = rowp[node + 1];
    float acc = 0.0f;
    int e = beg;
    for (; e + 8 <= end; e += 8) {
        int s0 = csr[e + slot];
        int s1 = csr[e + 4 + slot];
        float v0 = gs[s0 * 16 + f];
        float v1 = gs[s1 * 16 + f];
        acc += v0 + v1;
    }
    for (; e < end; e += 4) {
        if (e + slot < end) {
            int s = csr[e + slot];
            acc += gs[s * 16 + f];
        }
    }
    // reduce the 4 edge slots (lanes 0..15 end up with the total)
    acc += __shfl_down(acc, 32, 64);
    acc += __shfl_down(acc, 16, 64);
    if (lane < 16)
        a[(size_t)node * EMB + fb * 16 + lane] =
            dinv[node] * (acc + gs[node * 16 + lane]);
}

// ---------------------------------------------------------------------------
// Register-tiled GEMM + bias + tanh (+ optional dinv prescale).
// LAYOUT: 0 = row-major out[node][64]; 1 = slab out[fb][node][16].
// ---------------------------------------------------------------------------

template <int K, bool PRESCALE, int LAYOUT>
__global__ __launch_bounds__(256) void gemm_tile_kernel(const float* __restrict__ in,
                                                        const float* __restrict__ W,
                                                        const float* __restrict__ b,
                                                        const float* __restrict__ dinv,
                                                        float* __restrict__ out, int n) {
    __shared__ float sIn[64 * (K + 1)];
    __shared__ float sW[K * EMB];
    int tid = threadIdx.x;
    int base = blockIdx.x * 64;
    for (int i = tid; i < K * EMB; i += 256) sW[i] = W[i];
    for (int i = tid; i < 64 * K; i += 256) {
        int r = i / K, c = i - r * K;
        int node = base + r;
        sIn[r * (K + 1) + c] = (node < n) ? in[(size_t)node * K + c] : 0.0f;
    }
    __syncthreads();
    int tx = tid & 15, ty = tid >> 4;
    int f0 = tx * 4, n0 = ty * 4;
    float acc[4][4];
#pragma unroll
    for (int i = 0; i < 4; ++i)
#pragma unroll
        for (int j = 0; j < 4; ++j) acc[i][j] = b[f0 + j];
#pragma unroll 8
    for (int k = 0; k < K; ++k) {
        float a0 = sIn[(n0 + 0) * (K + 1) + k];
        float a1 = sIn[(n0 + 1) * (K + 1) + k];
        float a2 = sIn[(n0 + 2) * (K + 1) + k];
        float a3 = sIn[(n0 + 3) * (K + 1) + k];
        float4 wv = *(const float4*)&sW[k * EMB + f0];
        acc[0][0] = fmaf(a0, wv.x, acc[0][0]);
        acc[0][1] = fmaf(a0, wv.y, acc[0][1]);
        acc[0][2] = fmaf(a0, wv.z, acc[0][2]);
        acc[0][3] = fmaf(a0, wv.w, acc[0][3]);
        acc[1][0] = fmaf(a1, wv.x, acc[1][0]);
        acc[1][1] = fmaf(a1, wv.y, acc[1][1]);
        acc[1][2] = fmaf(a1, wv.z, acc[1][2]);
        acc[1][3] = fmaf(a1, wv.w, acc[1][3]);
        acc[2][0] = fmaf(a2, wv.x, acc[2][0]);
        acc[2][1] = fmaf(a2, wv.y, acc[2][1]);
        acc[2][2] = fmaf(a2, wv.z, acc[2][2]);
        acc[2][3] = fmaf(a2, wv.w, acc[2][3]);
        acc[3][0] = fmaf(a3, wv.x, acc[3][0]);
        acc[3][1] = fmaf(a3, wv.y, acc[3][1]);
        acc[3][2] = fmaf(a3, wv.z, acc[3][2]);
        acc[3][3] = fmaf(a3, wv.w, acc[3][3]);
    }
    int fb = f0 >> 4, col = f0 & 15;
#pragma unroll
    for (int i = 0; i < 4; ++i) {
        int node = base + n0 + i;
        if (node < n) {
            float dv = PRESCALE ? dinv[node] : 1.0f;
            float4 o;
            o.x = tanhf(acc[i][0]) * dv;
            o.y = tanhf(acc[i][1]) * dv;
            o.z = tanhf(acc[i][2]) * dv;
            o.w = tanhf(acc[i][3]) * dv;
            if (LAYOUT == 0)
                *(float4*)&out[(size_t)node * EMB + f0] = o;
            else
                *(float4*)&out[(size_t)fb * N_NODES * 16 + node * 16 + col] = o;
        }
    }
}

// ---------------------------------------------------------------------------
// Fused pooling (segment max + mean) + output GEMV: one block per graph
// ---------------------------------------------------------------------------

__global__ __launch_bounds__(256) void pool_kernel(const float* __restrict__ h,
                                                   const int* __restrict__ gstart,
                                                   const float* __restrict__ Wout,
                                                   const float* __restrict__ bout,
                                                   float* __restrict__ out, int ng) {
    __shared__ float smx[4][EMB];
    __shared__ float ssm[4][EMB];
    int g = blockIdx.x;
    if (g >= ng) return;
    int w = threadIdx.x >> 6, lane = threadIdx.x & 63;
    int beg = gstart[g], end = gstart[g + 1];
    float mx = -3.0e38f, sm = 0.0f;
    for (int i = beg + w; i < end; i += 4) {
        float v = h[(size_t)i * EMB + lane];
        mx = fmaxf(mx, v);
        sm += v;
    }
    smx[w][lane] = mx;
    ssm[w][lane] = sm;
    __syncthreads();
    if (w == 0) {
        mx = fmaxf(fmaxf(smx[0][lane], smx[1][lane]), fmaxf(smx[2][lane], smx[3][lane]));
        sm = ssm[0][lane] + ssm[1][lane] + ssm[2][lane] + ssm[3][lane];
        float mean = sm / (float)(end - beg);
        float r = mx * Wout[lane] + mean * Wout[EMB + lane];
#pragma unroll
        for (int off = 32; off; off >>= 1) r += __shfl_down(r, off, 64);
        if (lane == 0) out[g] = r + bout[0];
    }
}

// ---------------------------------------------------------------------------

extern "C" void kernel_launch(void* const* d_in, const int* in_sizes, int n_in,
                              void* d_out, int out_size, void* d_ws, size_t ws_size,
                              hipStream_t stream) {
    const float* x     = (const float*)d_in[0];
    const int*   ei    = (const int*)d_in[1];
    const int*   batch = (const int*)d_in[2];
    const float* W0 = (const float*)d_in[3];
    const float* b0 = (const float*)d_in[4];
    const float* W1 = (const float*)d_in[5];
    const float* b1 = (const float*)d_in[6];
    const float* W2 = (const float*)d_in[7];
    const float* b2 = (const float*)d_in[8];
    const float* W3 = (const float*)d_in[9];
    const float* b3 = (const float*)d_in[10];
    const float* Wout = (const float*)d_in[11];
    const float* bout = (const float*)d_in[12];
    float* out = (float*)d_out;

    // workspace layout (~31 MB); cntk+rank alias a_buf (dead until agg9)
    char* ws = (char*)d_ws;
    float* g_buf = (float*)ws;  ws += (size_t)N_NODES * EMB * 4;   // slab or row
    float* a_buf = (float*)ws;  ws += (size_t)N_NODES * EMB * 4;
    int*   csr   = (int*)ws;    ws += (size_t)N_EDGES * 4;
    int*   cnt   = (int*)ws;    ws += (size_t)N_NODES * 4;
    int*   rowp  = (int*)ws;    ws += (size_t)(N_NODES + 1) * 4;
    float* dinv  = (float*)ws;  ws += (size_t)N_NODES * 4;
    int*   gstart= (int*)ws;    ws += (size_t)(N_GRAPHS + 1) * 4;
    int*   bsum  = (int*)ws;    ws += (size_t)SCAN_NB * 4;
    int*   cntk  = (int*)a_buf;                             // KSPLIT*N ints
    int*   rank  = (int*)a_buf + (size_t)KSPLIT * N_NODES;  // NE ints

    const int* srcp = ei;
    const int* dstp = ei + N_EDGES;

    hipMemsetAsync(cntk, 0, (size_t)KSPLIT * N_NODES * 4, stream);

    int ebl = (N_EDGES + 255) / 256;
    rank_kernel<<<ebl, 256, 0, stream>>>(dstp, cntk, rank, N_EDGES);
    merge_kernel<<<SCAN_NB, 256, 0, stream>>>(cntk, x, batch, cnt, bsum, dinv, g_buf,
                                              gstart, N_NODES);
    scanfill_kernel<<<SCAN_NB, 256, 0, stream>>>(cnt, bsum, rowp, N_NODES);
    fill2_kernel<<<ebl, 256, 0, stream>>>(srcp, dstp, rank, rowp, cntk, csr, N_EDGES);

    int wbl = (N_NODES + 3) / 4;          // agg9: 4 waves (nodes) per block
    int gbl = (N_NODES + 63) / 64;        // gemm: 64 nodes per block

    // layer 0: g0 (row-major 9-dim) -> a -> gemm -> g slabs
    agg9_kernel<<<wbl, 256, 0, stream>>>(g_buf, csr, rowp, dinv, a_buf, N_NODES);
    gemm_tile_kernel<N_FEAT, true, 1><<<gbl, 256, 0, stream>>>(a_buf, W0, b0, dinv,
                                                               g_buf, N_NODES);
    // layers 1..2: slab-gather agg -> row-major a -> gemm -> g slabs
    agg64_fb_kernel<<<FB * NBPF, 256, 0, stream>>>(g_buf, csr, rowp, dinv, a_buf, N_NODES);
    gemm_tile_kernel<EMB, true, 1><<<gbl, 256, 0, stream>>>(a_buf, W1, b1, dinv,
                                                            g_buf, N_NODES);
    agg64_fb_kernel<<<FB * NBPF, 256, 0, stream>>>(g_buf, csr, rowp, dinv, a_buf, N_NODES);
    gemm_tile_kernel<EMB, true, 1><<<gbl, 256, 0, stream>>>(a_buf, W2, b2, dinv,
                                                            g_buf, N_NODES);
    // layer 3: slab-gather agg -> row-major a -> gemm -> row-major h (for pool)
    agg64_fb_kernel<<<FB * NBPF, 256, 0, stream>>>(g_buf, csr, rowp, dinv, a_buf, N_NODES);
    gemm_tile_kernel<EMB, false, 0><<<gbl, 256, 0, stream>>>(a_buf, W3, b3, dinv,
                                                             g_buf, N_NODES);

    pool_kernel<<<N_GRAPHS, 256, 0, stream>>>(g_buf, gstart, Wout, bout, out, N_GRAPHS);
}

// Round 10
// 381.351 us; speedup vs baseline: 1.3976x; 1.3976x over previous
//
#include <hip/hip_runtime.h>

#define N_NODES  50000
#define N_EDGES  1200000
#define N_GRAPHS 1024
#define N_FEAT   9
#define EMB      64
#define SCAN_NB  ((N_NODES + 255) / 256)   // 196 blocks
#define KSPLIT   16                        // histogram split factor

// ---------------------------------------------------------------------------
// CSR build (validated round 8). g = dinv*h prescale kills edge weights:
//   agg_i = dinv_i * ( g_i + sum_{e:(src->i)} g[src_e] )
// ---------------------------------------------------------------------------

__global__ __launch_bounds__(256) void rank_kernel(const int* __restrict__ dst,
                                                   int* __restrict__ cntk,
                                                   int* __restrict__ rank, int ne) {
    int i = blockIdx.x * blockDim.x + threadIdx.x;
    if (i < ne) {
        int k = i & (KSPLIT - 1);
        rank[i] = atomicAdd(&cntk[k * N_NODES + dst[i]], 1);
    }
}

// per-node: cntk -> per-k exclusive offsets, cnt totals, dinv, g0 = dinv*x,
// per-block sums for the scan, fused graph-boundary detection
__global__ __launch_bounds__(256) void merge_kernel(int* __restrict__ cntk,
                                                    const float* __restrict__ x,
                                                    const int* __restrict__ batch,
                                                    int* __restrict__ cnt,
                                                    int* __restrict__ bsum,
                                                    float* __restrict__ dinv,
                                                    float* __restrict__ g0,
                                                    int* __restrict__ gstart, int n) {
    __shared__ int sw[4];
    int t = threadIdx.x;
    int i = blockIdx.x * 256 + t;
    int total = 0;
    if (i < n) {
        int s = 0;
#pragma unroll
        for (int k = 0; k < KSPLIT; ++k) {
            int c = cntk[k * N_NODES + i];
            cntk[k * N_NODES + i] = s;
            s += c;
        }
        total = s;
        cnt[i] = s;
        float d = (float)s + 1.0f;
        float dv = rsqrtf(d);
        dinv[i] = dv;
#pragma unroll
        for (int f = 0; f < N_FEAT; ++f)
            g0[i * N_FEAT + f] = dv * x[i * N_FEAT + f];
        int b = batch[i];
        if (i == 0 || batch[i - 1] != b) gstart[b] = i;
        if (i == 0) gstart[N_GRAPHS] = n;
    }
    int r = total;
#pragma unroll
    for (int off = 32; off; off >>= 1) r += __shfl_down(r, off, 64);
    if ((t & 63) == 0) sw[t >> 6] = r;
    __syncthreads();
    if (t == 0) bsum[blockIdx.x] = sw[0] + sw[1] + sw[2] + sw[3];
}

__global__ __launch_bounds__(256) void scanfill_kernel(const int* __restrict__ cnt,
                                                       const int* __restrict__ bsum,
                                                       int* __restrict__ rowp, int n) {
    __shared__ int sw[4];
    __shared__ int s_off;
    __shared__ int lds[256];
    int t = threadIdx.x;
    int p = (t < blockIdx.x) ? bsum[t] : 0;
#pragma unroll
    for (int off = 32; off; off >>= 1) p += __shfl_down(p, off, 64);
    if ((t & 63) == 0) sw[t >> 6] = p;
    __syncthreads();
    if (t == 0) s_off = sw[0] + sw[1] + sw[2] + sw[3];
    int i = blockIdx.x * 256 + t;
    int v = (i < n) ? cnt[i] : 0;
    lds[t] = v;
    __syncthreads();
    for (int off = 1; off < 256; off <<= 1) {
        int u = (t >= off) ? lds[t - off] : 0;
        __syncthreads();
        lds[t] += u;
        __syncthreads();
    }
    if (i < n) rowp[i] = s_off + lds[t] - v;
    if (i == 0) rowp[n] = N_EDGES;
}

__global__ __launch_bounds__(256) void fill2_kernel(const int* __restrict__ src,
                                                    const int* __restrict__ dst,
                                                    const int* __restrict__ rank,
                                                    const int* __restrict__ rowp,
                                                    const int* __restrict__ cntk,
                                                    int* __restrict__ csr, int ne) {
    int i = blockIdx.x * blockDim.x + threadIdx.x;
    if (i >= ne) return;
    int d = dst[i];
    int k = i & (KSPLIT - 1);
    csr[rowp[d] + cntk[k * N_NODES + d] + rank[i]] = src[i];
}

// ---------------------------------------------------------------------------
// Layer-0 aggregation (9-dim), row-major g0
// ---------------------------------------------------------------------------

__global__ __launch_bounds__(256) void agg9_kernel(const float* __restrict__ g0,
                                                   const int* __restrict__ csr,
                                                   const int* __restrict__ rowp,
                                                   const float* __restrict__ dinv,
                                                   float* __restrict__ a, int n) {
    int wave = blockIdx.x * (blockDim.x >> 6) + (threadIdx.x >> 6);
    int lane = threadIdx.x & 63;
    if (wave >= n) return;
    int beg = rowp[wave], end = rowp[wave + 1];
    int slot = lane / 9;
    int f    = lane - slot * 9;
    float p = 0.0f;
    int e = beg;
    for (; e + 7 <= end; e += 7) {
        if (slot < 7) {
            int s = csr[e + slot];
            p += g0[s * N_FEAT + f];
        }
    }
    for (; e < end; ++e) {
        if (lane < N_FEAT) {
            int s = csr[e];
            p += g0[s * N_FEAT + lane];
        }
    }
    float tot = p;
#pragma unroll
    for (int s = 1; s < 7; ++s) {
        float t = __shfl(p, 9 * s + lane, 64);
        if (lane < N_FEAT) tot += t;
    }
    if (lane < N_FEAT)
        a[wave * N_FEAT + lane] = dinv[wave] * (tot + g0[wave * N_FEAT + lane]);
}

// ---------------------------------------------------------------------------
// Register-tiled GEMM + bias + tanh + dinv prescale (layer 0 only, K=9)
// ---------------------------------------------------------------------------

template <int K, bool PRESCALE>
__global__ __launch_bounds__(256) void gemm_tile_kernel(const float* __restrict__ in,
                                                        const float* __restrict__ W,
                                                        const float* __restrict__ b,
                                                        const float* __restrict__ dinv,
                                                        float* __restrict__ out, int n) {
    __shared__ float sIn[64 * (K + 1)];
    __shared__ float sW[K * EMB];
    int tid = threadIdx.x;
    int base = blockIdx.x * 64;
    for (int i = tid; i < K * EMB; i += 256) sW[i] = W[i];
    for (int i = tid; i < 64 * K; i += 256) {
        int r = i / K, c = i - r * K;
        int node = base + r;
        sIn[r * (K + 1) + c] = (node < n) ? in[(size_t)node * K + c] : 0.0f;
    }
    __syncthreads();
    int tx = tid & 15, ty = tid >> 4;
    int f0 = tx * 4, n0 = ty * 4;
    float acc[4][4];
#pragma unroll
    for (int i = 0; i < 4; ++i)
#pragma unroll
        for (int j = 0; j < 4; ++j) acc[i][j] = b[f0 + j];
#pragma unroll
    for (int k = 0; k < K; ++k) {
        float a0 = sIn[(n0 + 0) * (K + 1) + k];
        float a1 = sIn[(n0 + 1) * (K + 1) + k];
        float a2 = sIn[(n0 + 2) * (K + 1) + k];
        float a3 = sIn[(n0 + 3) * (K + 1) + k];
        float4 wv = *(const float4*)&sW[k * EMB + f0];
        acc[0][0] = fmaf(a0, wv.x, acc[0][0]);
        acc[0][1] = fmaf(a0, wv.y, acc[0][1]);
        acc[0][2] = fmaf(a0, wv.z, acc[0][2]);
        acc[0][3] = fmaf(a0, wv.w, acc[0][3]);
        acc[1][0] = fmaf(a1, wv.x, acc[1][0]);
        acc[1][1] = fmaf(a1, wv.y, acc[1][1]);
        acc[1][2] = fmaf(a1, wv.z, acc[1][2]);
        acc[1][3] = fmaf(a1, wv.w, acc[1][3]);
        acc[2][0] = fmaf(a2, wv.x, acc[2][0]);
        acc[2][1] = fmaf(a2, wv.y, acc[2][1]);
        acc[2][2] = fmaf(a2, wv.z, acc[2][2]);
        acc[2][3] = fmaf(a2, wv.w, acc[2][3]);
        acc[3][0] = fmaf(a3, wv.x, acc[3][0]);
        acc[3][1] = fmaf(a3, wv.y, acc[3][1]);
        acc[3][2] = fmaf(a3, wv.z, acc[3][2]);
        acc[3][3] = fmaf(a3, wv.w, acc[3][3]);
    }
#pragma unroll
    for (int i = 0; i < 4; ++i) {
        int node = base + n0 + i;
        if (node < n) {
            float dv = PRESCALE ? dinv[node] : 1.0f;
            float4 o;
            o.x = tanhf(acc[i][0]) * dv;
            o.y = tanhf(acc[i][1]) * dv;
            o.z = tanhf(acc[i][2]) * dv;
            o.w = tanhf(acc[i][3]) * dv;
            *(float4*)&out[(size_t)node * EMB + f0] = o;
        }
    }
}

// ---------------------------------------------------------------------------
// FUSED layer (1..3): aggregation (row-major float2 gathers) -> LDS (transposed)
// -> 64x64 GEMM + bias + tanh (+ dinv prescale) -> row-major out.
// 64-node tile, 512 threads (8 waves). gin and gout MUST be distinct buffers.
// ---------------------------------------------------------------------------

template <bool PRESCALE>
__global__ __launch_bounds__(512) void fused_kernel(const float* __restrict__ gin,
                                                    const int* __restrict__ csr,
                                                    const int* __restrict__ rowp,
                                                    const float* __restrict__ dinv,
                                                    const float* __restrict__ W,
                                                    const float* __restrict__ b,
                                                    float* __restrict__ gout, int n) {
    __shared__ float sA[EMB * 65];       // transposed agg result: sA[f][node]
    __shared__ float sW[EMB * EMB];
    int tid = threadIdx.x;
    int base = blockIdx.x * 64;
    // stage W (16 KB) as float4
    for (int i = tid; i < EMB * 16; i += 512)
        ((float4*)sW)[i] = ((const float4*)W)[i];
    // ---- aggregation: wave w handles local nodes w, w+8, ..., w+56
    int w = tid >> 6, lane = tid & 63;
    int slot = lane >> 5;                // 0/1: which edge of the pair
    int j = lane & 31;                   // feature-pair index (feats 2j, 2j+1)
    const float2* g2 = (const float2*)gin;
    for (int t = 0; t < 8; ++t) {
        int r = w + 8 * t;
        int node = base + r;
        float ax = 0.0f, ay = 0.0f;
        if (node < n) {
            int beg = rowp[node], end = rowp[node + 1];
            int e = beg;
            for (; e + 16 <= end; e += 16) {
                int s0 = csr[e + 0 + slot],  s1 = csr[e + 2 + slot];
                int s2 = csr[e + 4 + slot],  s3 = csr[e + 6 + slot];
                int s4 = csr[e + 8 + slot],  s5 = csr[e + 10 + slot];
                int s6 = csr[e + 12 + slot], s7 = csr[e + 14 + slot];
                float2 v0 = g2[(size_t)s0 * 32 + j], v1 = g2[(size_t)s1 * 32 + j];
                float2 v2 = g2[(size_t)s2 * 32 + j], v3 = g2[(size_t)s3 * 32 + j];
                float2 v4 = g2[(size_t)s4 * 32 + j], v5 = g2[(size_t)s5 * 32 + j];
                float2 v6 = g2[(size_t)s6 * 32 + j], v7 = g2[(size_t)s7 * 32 + j];
                ax += ((v0.x + v1.x) + (v2.x + v3.x)) + ((v4.x + v5.x) + (v6.x + v7.x));
                ay += ((v0.y + v1.y) + (v2.y + v3.y)) + ((v4.y + v5.y) + (v6.y + v7.y));
            }
            for (; e + 2 <= end; e += 2) {
                int s = csr[e + slot];
                float2 v = g2[(size_t)s * 32 + j];
                ax += v.x; ay += v.y;
            }
            if (e < end && slot == 0) {
                float2 v = g2[(size_t)csr[e] * 32 + j];
                ax += v.x; ay += v.y;
            }
        }
        ax += __shfl_down(ax, 32, 64);
        ay += __shfl_down(ay, 32, 64);
        if (slot == 0) {
            float ox = 0.0f, oy = 0.0f;
            if (node < n) {
                float2 self = g2[(size_t)node * 32 + j];
                float dv = dinv[node];
                ox = dv * (ax + self.x);
                oy = dv * (ay + self.y);
            }
            sA[(2 * j) * 65 + r]     = ox;
            sA[(2 * j + 1) * 65 + r] = oy;
        }
    }
    __syncthreads();
    // ---- GEMM: thread (tx,ty): feats f0..f0+3, nodes n0..n0+1
    int tx = tid & 15, ty = tid >> 4;
    int f0 = tx * 4, n0 = ty * 2;
    float4 bb = ((const float4*)b)[tx];
    float acc0[4] = {bb.x, bb.y, bb.z, bb.w};
    float acc1[4] = {bb.x, bb.y, bb.z, bb.w};
#pragma unroll 8
    for (int k = 0; k < EMB; ++k) {
        float a0 = sA[k * 65 + n0];
        float a1 = sA[k * 65 + n0 + 1];
        float4 wv = ((const float4*)sW)[k * 16 + tx];
        acc0[0] = fmaf(a0, wv.x, acc0[0]);
        acc0[1] = fmaf(a0, wv.y, acc0[1]);
        acc0[2] = fmaf(a0, wv.z, acc0[2]);
        acc0[3] = fmaf(a0, wv.w, acc0[3]);
        acc1[0] = fmaf(a1, wv.x, acc1[0]);
        acc1[1] = fmaf(a1, wv.y, acc1[1]);
        acc1[2] = fmaf(a1, wv.z, acc1[2]);
        acc1[3] = fmaf(a1, wv.w, acc1[3]);
    }
    int node0 = base + n0;
    if (node0 < n) {
        float dv = PRESCALE ? dinv[node0] : 1.0f;
        float4 o;
        o.x = tanhf(acc0[0]) * dv;
        o.y = tanhf(acc0[1]) * dv;
        o.z = tanhf(acc0[2]) * dv;
        o.w = tanhf(acc0[3]) * dv;
        *(float4*)&gout[(size_t)node0 * EMB + f0] = o;
    }
    if (node0 + 1 < n) {
        float dv = PRESCALE ? dinv[node0 + 1] : 1.0f;
        float4 o;
        o.x = tanhf(acc1[0]) * dv;
        o.y = tanhf(acc1[1]) * dv;
        o.z = tanhf(acc1[2]) * dv;
        o.w = tanhf(acc1[3]) * dv;
        *(float4*)&gout[(size_t)(node0 + 1) * EMB + f0] = o;
    }
}

// ---------------------------------------------------------------------------
// Fused pooling (segment max + mean) + output GEMV: one block per graph
// ---------------------------------------------------------------------------

__global__ __launch_bounds__(256) void pool_kernel(const float* __restrict__ h,
                                                   const int* __restrict__ gstart,
                                                   const float* __restrict__ Wout,
                                                   const float* __restrict__ bout,
                                                   float* __restrict__ out, int ng) {
    __shared__ float smx[4][EMB];
    __shared__ float ssm[4][EMB];
    int g = blockIdx.x;
    if (g >= ng) return;
    int w = threadIdx.x >> 6, lane = threadIdx.x & 63;
    int beg = gstart[g], end = gstart[g + 1];
    float mx = -3.0e38f, sm = 0.0f;
    for (int i = beg + w; i < end; i += 4) {
        float v = h[(size_t)i * EMB + lane];
        mx = fmaxf(mx, v);
        sm += v;
    }
    smx[w][lane] = mx;
    ssm[w][lane] = sm;
    __syncthreads();
    if (w == 0) {
        mx = fmaxf(fmaxf(smx[0][lane], smx[1][lane]), fmaxf(smx[2][lane], smx[3][lane]));
        sm = ssm[0][lane] + ssm[1][lane] + ssm[2][lane] + ssm[3][lane];
        float mean = sm / (float)(end - beg);
        float r = mx * Wout[lane] + mean * Wout[EMB + lane];
#pragma unroll
        for (int off = 32; off; off >>= 1) r += __shfl_down(r, off, 64);
        if (lane == 0) out[g] = r + bout[0];
    }
}

// ---------------------------------------------------------------------------

extern "C" void kernel_launch(void* const* d_in, const int* in_sizes, int n_in,
                              void* d_out, int out_size, void* d_ws, size_t ws_size,
                              hipStream_t stream) {
    const float* x     = (const float*)d_in[0];
    const int*   ei    = (const int*)d_in[1];
    const int*   batch = (const int*)d_in[2];
    const float* W0 = (const float*)d_in[3];
    const float* b0 = (const float*)d_in[4];
    const float* W1 = (const float*)d_in[5];
    const float* b1 = (const float*)d_in[6];
    const float* W2 = (const float*)d_in[7];
    const float* b2 = (const float*)d_in[8];
    const float* W3 = (const float*)d_in[9];
    const float* b3 = (const float*)d_in[10];
    const float* Wout = (const float*)d_in[11];
    const float* bout = (const float*)d_in[12];
    float* out = (float*)d_out;

    // workspace (~31 MB); cntk+rank alias a_buf (dead after fill2)
    char* ws = (char*)d_ws;
    float* g_buf = (float*)ws;  ws += (size_t)N_NODES * EMB * 4;
    float* a_buf = (float*)ws;  ws += (size_t)N_NODES * EMB * 4;
    int*   csr   = (int*)ws;    ws += (size_t)N_EDGES * 4;
    int*   cnt   = (int*)ws;    ws += (size_t)N_NODES * 4;
    int*   rowp  = (int*)ws;    ws += (size_t)(N_NODES + 1) * 4;
    float* dinv  = (float*)ws;  ws += (size_t)N_NODES * 4;
    int*   gstart= (int*)ws;    ws += (size_t)(N_GRAPHS + 1) * 4;
    int*   bsum  = (int*)ws;    ws += (size_t)SCAN_NB * 4;
    int*   cntk  = (int*)a_buf;
    int*   rank  = (int*)a_buf + (size_t)KSPLIT * N_NODES;

    const int* srcp = ei;
    const int* dstp = ei + N_EDGES;

    hipMemsetAsync(cntk, 0, (size_t)KSPLIT * N_NODES * 4, stream);

    int ebl = (N_EDGES + 255) / 256;
    rank_kernel<<<ebl, 256, 0, stream>>>(dstp, cntk, rank, N_EDGES);
    merge_kernel<<<SCAN_NB, 256, 0, stream>>>(cntk, x, batch, cnt, bsum, dinv, g_buf,
                                              gstart, N_NODES);
    scanfill_kernel<<<SCAN_NB, 256, 0, stream>>>(cnt, bsum, rowp, N_NODES);
    fill2_kernel<<<ebl, 256, 0, stream>>>(srcp, dstp, rank, rowp, cntk, csr, N_EDGES);

    int wbl = (N_NODES + 3) / 4;          // agg9: 4 waves per block
    int gbl = (N_NODES + 63) / 64;        // 64-node tiles (782 blocks)

    // layer 0: agg9 on g0 (in g_buf) -> a_buf, then 9->64 GEMM -> g_buf
    agg9_kernel<<<wbl, 256, 0, stream>>>(g_buf, csr, rowp, dinv, a_buf, N_NODES);
    gemm_tile_kernel<N_FEAT, true><<<gbl, 256, 0, stream>>>(a_buf, W0, b0, dinv,
                                                            g_buf, N_NODES);
    // layers 1..3 fused (ping-pong g_buf <-> a_buf)
    fused_kernel<true><<<gbl, 512, 0, stream>>>(g_buf, csr, rowp, dinv, W1, b1,
                                                a_buf, N_NODES);
    fused_kernel<true><<<gbl, 512, 0, stream>>>(a_buf, csr, rowp, dinv, W2, b2,
                                                g_buf, N_NODES);
    fused_kernel<false><<<gbl, 512, 0, stream>>>(g_buf, csr, rowp, dinv, W3, b3,
                                                 a_buf, N_NODES);

    pool_kernel<<<N_GRAPHS, 256, 0, stream>>>(a_buf, gstart, Wout, bout, out, N_GRAPHS);
}

// Round 13
// 358.599 us; speedup vs baseline: 1.4863x; 1.0634x over previous
//
#include <hip/hip_runtime.h>

#define N_NODES  50000
#define N_EDGES  1200000
#define N_GRAPHS 1024
#define N_FEAT   9
#define EMB      64
#define SCAN_NB  ((N_NODES + 255) / 256)   // 196 blocks
#define KSPLIT   16                        // histogram split factor

// ---------------------------------------------------------------------------
// CSR build (validated round 8). g = dinv*h prescale kills edge weights:
//   agg_i = dinv_i * ( g_i + sum_{e:(src->i)} g[src_e] )
// ---------------------------------------------------------------------------

__global__ __launch_bounds__(256) void rank_kernel(const int* __restrict__ dst,
                                                   int* __restrict__ cntk,
                                                   int* __restrict__ rank, int ne) {
    int i = blockIdx.x * blockDim.x + threadIdx.x;
    if (i < ne) {
        int k = i & (KSPLIT - 1);
        rank[i] = atomicAdd(&cntk[k * N_NODES + dst[i]], 1);
    }
}

// per-node: cntk -> per-k exclusive offsets, cnt totals, dinv, g0 = dinv*x,
// per-block sums for the scan, fused graph-boundary detection
__global__ __launch_bounds__(256) void merge_kernel(int* __restrict__ cntk,
                                                    const float* __restrict__ x,
                                                    const int* __restrict__ batch,
                                                    int* __restrict__ cnt,
                                                    int* __restrict__ bsum,
                                                    float* __restrict__ dinv,
                                                    float* __restrict__ g0,
                                                    int* __restrict__ gstart, int n) {
    __shared__ int sw[4];
    int t = threadIdx.x;
    int i = blockIdx.x * 256 + t;
    int total = 0;
    if (i < n) {
        int s = 0;
#pragma unroll
        for (int k = 0; k < KSPLIT; ++k) {
            int c = cntk[k * N_NODES + i];
            cntk[k * N_NODES + i] = s;
            s += c;
        }
        total = s;
        cnt[i] = s;
        float d = (float)s + 1.0f;
        float dv = rsqrtf(d);
        dinv[i] = dv;
#pragma unroll
        for (int f = 0; f < N_FEAT; ++f)
            g0[i * N_FEAT + f] = dv * x[i * N_FEAT + f];
        int b = batch[i];
        if (i == 0 || batch[i - 1] != b) gstart[b] = i;
        if (i == 0) gstart[N_GRAPHS] = n;
    }
    int r = total;
#pragma unroll
    for (int off = 32; off; off >>= 1) r += __shfl_down(r, off, 64);
    if ((t & 63) == 0) sw[t >> 6] = r;
    __syncthreads();
    if (t == 0) bsum[blockIdx.x] = sw[0] + sw[1] + sw[2] + sw[3];
}

__global__ __launch_bounds__(256) void scanfill_kernel(const int* __restrict__ cnt,
                                                       const int* __restrict__ bsum,
                                                       int* __restrict__ rowp, int n) {
    __shared__ int sw[4];
    __shared__ int s_off;
    __shared__ int lds[256];
    int t = threadIdx.x;
    int p = (t < blockIdx.x) ? bsum[t] : 0;
#pragma unroll
    for (int off = 32; off; off >>= 1) p += __shfl_down(p, off, 64);
    if ((t & 63) == 0) sw[t >> 6] = p;
    __syncthreads();
    if (t == 0) s_off = sw[0] + sw[1] + sw[2] + sw[3];
    int i = blockIdx.x * 256 + t;
    int v = (i < n) ? cnt[i] : 0;
    lds[t] = v;
    __syncthreads();
    for (int off = 1; off < 256; off <<= 1) {
        int u = (t >= off) ? lds[t - off] : 0;
        __syncthreads();
        lds[t] += u;
        __syncthreads();
    }
    if (i < n) rowp[i] = s_off + lds[t] - v;
    if (i == 0) rowp[n] = N_EDGES;
}

__global__ __launch_bounds__(256) void fill2_kernel(const int* __restrict__ src,
                                                    const int* __restrict__ dst,
                                                    const int* __restrict__ rank,
                                                    const int* __restrict__ rowp,
                                                    const int* __restrict__ cntk,
                                                    int* __restrict__ csr, int ne) {
    int i = blockIdx.x * blockDim.x + threadIdx.x;
    if (i >= ne) return;
    int d = dst[i];
    int k = i & (KSPLIT - 1);
    csr[rowp[d] + cntk[k * N_NODES + d] + rank[i]] = src[i];
}

// ---------------------------------------------------------------------------
// Layer-0 aggregation (9-dim), row-major g0
// ---------------------------------------------------------------------------

__global__ __launch_bounds__(256) void agg9_kernel(const float* __restrict__ g0,
                                                   const int* __restrict__ csr,
                                                   const int* __restrict__ rowp,
                                                   const float* __restrict__ dinv,
                                                   float* __restrict__ a, int n) {
    int wave = blockIdx.x * (blockDim.x >> 6) + (threadIdx.x >> 6);
    int lane = threadIdx.x & 63;
    if (wave >= n) return;
    int beg = rowp[wave], end = rowp[wave + 1];
    int slot = lane / 9;
    int f    = lane - slot * 9;
    float p = 0.0f;
    int e = beg;
    for (; e + 7 <= end; e += 7) {
        if (slot < 7) {
            int s = csr[e + slot];
            p += g0[s * N_FEAT + f];
        }
    }
    for (; e < end; ++e) {
        if (lane < N_FEAT) {
            int s = csr[e];
            p += g0[s * N_FEAT + lane];
        }
    }
    float tot = p;
#pragma unroll
    for (int s = 1; s < 7; ++s) {
        float t = __shfl(p, 9 * s + lane, 64);
        if (lane < N_FEAT) tot += t;
    }
    if (lane < N_FEAT)
        a[wave * N_FEAT + lane] = dinv[wave] * (tot + g0[wave * N_FEAT + lane]);
}

// ---------------------------------------------------------------------------
// Register-tiled GEMM + bias + tanh + dinv prescale (layer 0 only, K=9)
// ---------------------------------------------------------------------------

template <int K, bool PRESCALE>
__global__ __launch_bounds__(256) void gemm_tile_kernel(const float* __restrict__ in,
                                                        const float* __restrict__ W,
                                                        const float* __restrict__ b,
                                                        const float* __restrict__ dinv,
                                                        float* __restrict__ out, int n) {
    __shared__ float sIn[64 * (K + 1)];
    __shared__ float sW[K * EMB];
    int tid = threadIdx.x;
    int base = blockIdx.x * 64;
    for (int i = tid; i < K * EMB; i += 256) sW[i] = W[i];
    for (int i = tid; i < 64 * K; i += 256) {
        int r = i / K, c = i - r * K;
        int node = base + r;
        sIn[r * (K + 1) + c] = (node < n) ? in[(size_t)node * K + c] : 0.0f;
    }
    __syncthreads();
    int tx = tid & 15, ty = tid >> 4;
    int f0 = tx * 4, n0 = ty * 4;
    float acc[4][4];
#pragma unroll
    for (int i = 0; i < 4; ++i)
#pragma unroll
        for (int j = 0; j < 4; ++j) acc[i][j] = b[f0 + j];
#pragma unroll
    for (int k = 0; k < K; ++k) {
        float a0 = sIn[(n0 + 0) * (K + 1) + k];
        float a1 = sIn[(n0 + 1) * (K + 1) + k];
        float a2 = sIn[(n0 + 2) * (K + 1) + k];
        float a3 = sIn[(n0 + 3) * (K + 1) + k];
        float4 wv = *(const float4*)&sW[k * EMB + f0];
        acc[0][0] = fmaf(a0, wv.x, acc[0][0]);
        acc[0][1] = fmaf(a0, wv.y, acc[0][1]);
        acc[0][2] = fmaf(a0, wv.z, acc[0][2]);
        acc[0][3] = fmaf(a0, wv.w, acc[0][3]);
        acc[1][0] = fmaf(a1, wv.x, acc[1][0]);
        acc[1][1] = fmaf(a1, wv.y, acc[1][1]);
        acc[1][2] = fmaf(a1, wv.z, acc[1][2]);
        acc[1][3] = fmaf(a1, wv.w, acc[1][3]);
        acc[2][0] = fmaf(a2, wv.x, acc[2][0]);
        acc[2][1] = fmaf(a2, wv.y, acc[2][1]);
        acc[2][2] = fmaf(a2, wv.z, acc[2][2]);
        acc[2][3] = fmaf(a2, wv.w, acc[2][3]);
        acc[3][0] = fmaf(a3, wv.x, acc[3][0]);
        acc[3][1] = fmaf(a3, wv.y, acc[3][1]);
        acc[3][2] = fmaf(a3, wv.z, acc[3][2]);
        acc[3][3] = fmaf(a3, wv.w, acc[3][3]);
    }
#pragma unroll
    for (int i = 0; i < 4; ++i) {
        int node = base + n0 + i;
        if (node < n) {
            float dv = PRESCALE ? dinv[node] : 1.0f;
            float4 o;
            o.x = tanhf(acc[i][0]) * dv;
            o.y = tanhf(acc[i][1]) * dv;
            o.z = tanhf(acc[i][2]) * dv;
            o.w = tanhf(acc[i][3]) * dv;
            *(float4*)&out[(size_t)node * EMB + f0] = o;
        }
    }
}

// ---------------------------------------------------------------------------
// FUSED layer (1..3), v2: 32-node tile, 512 threads (8 waves).
// Aggregation uses float4 gathers: lane = slot*16 + j; slot in 0..3 picks the
// edge, j in 0..15 picks the float4 (feats 4j..4j+3). One vmem instruction
// covers 4 edge-rows (1 KB). Agg result transposed into LDS sA[feat][node],
// then 32x64 GEMM + bias + tanh (+ dinv prescale).
// grid 1563 blocks -> ~6 blocks/CU; LDS 24.8 KB -> 4 blocks/CU (32 waves, max).
// ---------------------------------------------------------------------------

template <bool PRESCALE>
__global__ __launch_bounds__(512) void fused_kernel(const float* __restrict__ gin,
                                                    const int* __restrict__ csr,
                                                    const int* __restrict__ rowp,
                                                    const float* __restrict__ dinv,
                                                    const float* __restrict__ W,
                                                    const float* __restrict__ b,
                                                    float* __restrict__ gout, int n) {
    __shared__ float sA[EMB * 33];       // transposed agg result: sA[f][node]
    __shared__ float sW[EMB * EMB];
    int tid = threadIdx.x;
    int base = blockIdx.x * 32;
    // stage W (16 KB) as float4
    for (int i = tid; i < EMB * 16; i += 512)
        ((float4*)sW)[i] = ((const float4*)W)[i];
    // ---- aggregation: wave w handles local nodes w, w+8, w+16, w+24
    int w = tid >> 6, lane = tid & 63;
    int slot = lane >> 4;                // 0..3: edge within quad
    int j = lane & 15;                   // float4 index (feats 4j..4j+3)
    const float4* g4 = (const float4*)gin;
#pragma unroll
    for (int t = 0; t < 4; ++t) {
        int r = w + 8 * t;
        int node = base + r;
        float4 acc = {0.0f, 0.0f, 0.0f, 0.0f};
        if (node < n) {
            int beg = rowp[node], end = rowp[node + 1];
            int e = beg;
            for (; e + 16 <= end; e += 16) {
                int s0 = csr[e + slot];
                int s1 = csr[e + 4 + slot];
                int s2 = csr[e + 8 + slot];
                int s3 = csr[e + 12 + slot];
                float4 v0 = g4[(size_t)s0 * 16 + j];
                float4 v1 = g4[(size_t)s1 * 16 + j];
                float4 v2 = g4[(size_t)s2 * 16 + j];
                float4 v3 = g4[(size_t)s3 * 16 + j];
                acc.x += (v0.x + v1.x) + (v2.x + v3.x);
                acc.y += (v0.y + v1.y) + (v2.y + v3.y);
                acc.z += (v0.z + v1.z) + (v2.z + v3.z);
                acc.w += (v0.w + v1.w) + (v2.w + v3.w);
            }
            for (; e + 4 <= end; e += 4) {
                int s = csr[e + slot];
                float4 v = g4[(size_t)s * 16 + j];
                acc.x += v.x; acc.y += v.y; acc.z += v.z; acc.w += v.w;
            }
            if (e + slot < end) {
                int s = csr[e + slot];
                float4 v = g4[(size_t)s * 16 + j];
                acc.x += v.x; acc.y += v.y; acc.z += v.z; acc.w += v.w;
            }
        }
        // reduce the 4 slots: lanes 0..15 end with feature-j totals
        acc.x += __shfl_down(acc.x, 32, 64);
        acc.y += __shfl_down(acc.y, 32, 64);
        acc.z += __shfl_down(acc.z, 32, 64);
        acc.w += __shfl_down(acc.w, 32, 64);
        acc.x += __shfl_down(acc.x, 16, 64);
        acc.y += __shfl_down(acc.y, 16, 64);
        acc.z += __shfl_down(acc.z, 16, 64);
        acc.w += __shfl_down(acc.w, 16, 64);
        if (slot == 0) {
            float ox = 0.0f, oy = 0.0f, oz = 0.0f, ow = 0.0f;
            if (node < n) {
                float4 self = g4[(size_t)node * 16 + j];
                float dv = dinv[node];
                ox = dv * (acc.x + self.x);
                oy = dv * (acc.y + self.y);
                oz = dv * (acc.z + self.z);
                ow = dv * (acc.w + self.w);
            }
            sA[(4 * j + 0) * 33 + r] = ox;
            sA[(4 * j + 1) * 33 + r] = oy;
            sA[(4 * j + 2) * 33 + r] = oz;
            sA[(4 * j + 3) * 33 + r] = ow;
        }
    }
    __syncthreads();
    // ---- GEMM: thread (tx,ty): feats f0..f0+3 of node ty
    int tx = tid & 15, ty = tid >> 4;    // tx 0..15, ty 0..31
    int f0 = tx * 4;
    float4 bb = ((const float4*)b)[tx];
    float acc0 = bb.x, acc1 = bb.y, acc2 = bb.z, acc3 = bb.w;
#pragma unroll 8
    for (int k = 0; k < EMB; ++k) {
        float a0 = sA[k * 33 + ty];
        float4 wv = ((const float4*)sW)[k * 16 + tx];
        acc0 = fmaf(a0, wv.x, acc0);
        acc1 = fmaf(a0, wv.y, acc1);
        acc2 = fmaf(a0, wv.z, acc2);
        acc3 = fmaf(a0, wv.w, acc3);
    }
    int node0 = base + ty;
    if (node0 < n) {
        float dv = PRESCALE ? dinv[node0] : 1.0f;
        float4 o;
        o.x = tanhf(acc0) * dv;
        o.y = tanhf(acc1) * dv;
        o.z = tanhf(acc2) * dv;
        o.w = tanhf(acc3) * dv;
        *(float4*)&gout[(size_t)node0 * EMB + f0] = o;
    }
}

// ---------------------------------------------------------------------------
// Fused pooling (segment max + mean) + output GEMV: one block per graph
// ---------------------------------------------------------------------------

__global__ __launch_bounds__(256) void pool_kernel(const float* __restrict__ h,
                                                   const int* __restrict__ gstart,
                                                   const float* __restrict__ Wout,
                                                   const float* __restrict__ bout,
                                                   float* __restrict__ out, int ng) {
    __shared__ float smx[4][EMB];
    __shared__ float ssm[4][EMB];
    int g = blockIdx.x;
    if (g >= ng) return;
    int w = threadIdx.x >> 6, lane = threadIdx.x & 63;
    int beg = gstart[g], end = gstart[g + 1];
    float mx = -3.0e38f, sm = 0.0f;
    for (int i = beg + w; i < end; i += 4) {
        float v = h[(size_t)i * EMB + lane];
        mx = fmaxf(mx, v);
        sm += v;
    }
    smx[w][lane] = mx;
    ssm[w][lane] = sm;
    __syncthreads();
    if (w == 0) {
        mx = fmaxf(fmaxf(smx[0][lane], smx[1][lane]), fmaxf(smx[2][lane], smx[3][lane]));
        sm = ssm[0][lane] + ssm[1][lane] + ssm[2][lane] + ssm[3][lane];
        float mean = sm / (float)(end - beg);
        float r = mx * Wout[lane] + mean * Wout[EMB + lane];
#pragma unroll
        for (int off = 32; off; off >>= 1) r += __shfl_down(r, off, 64);
        if (lane == 0) out[g] = r + bout[0];
    }
}

// ---------------------------------------------------------------------------

extern "C" void kernel_launch(void* const* d_in, const int* in_sizes, int n_in,
                              void* d_out, int out_size, void* d_ws, size_t ws_size,
                              hipStream_t stream) {
    const float* x     = (const float*)d_in[0];
    const int*   ei    = (const int*)d_in[1];
    const int*   batch = (const int*)d_in[2];
    const float* W0 = (const float*)d_in[3];
    const float* b0 = (const float*)d_in[4];
    const float* W1 = (const float*)d_in[5];
    const float* b1 = (const float*)d_in[6];
    const float* W2 = (const float*)d_in[7];
    const float* b2 = (const float*)d_in[8];
    const float* W3 = (const float*)d_in[9];
    const float* b3 = (const float*)d_in[10];
    const float* Wout = (const float*)d_in[11];
    const float* bout = (const float*)d_in[12];
    float* out = (float*)d_out;

    // workspace (~31 MB); cntk+rank alias a_buf (dead after fill2)
    char* ws = (char*)d_ws;
    float* g_buf = (float*)ws;  ws += (size_t)N_NODES * EMB * 4;
    float* a_buf = (float*)ws;  ws += (size_t)N_NODES * EMB * 4;
    int*   csr   = (int*)ws;    ws += (size_t)N_EDGES * 4;
    int*   cnt   = (int*)ws;    ws += (size_t)N_NODES * 4;
    int*   rowp  = (int*)ws;    ws += (size_t)(N_NODES + 1) * 4;
    float* dinv  = (float*)ws;  ws += (size_t)N_NODES * 4;
    int*   gstart= (int*)ws;    ws += (size_t)(N_GRAPHS + 1) * 4;
    int*   bsum  = (int*)ws;    ws += (size_t)SCAN_NB * 4;
    int*   cntk  = (int*)a_buf;
    int*   rank  = (int*)a_buf + (size_t)KSPLIT * N_NODES;

    const int* srcp = ei;
    const int* dstp = ei + N_EDGES;

    hipMemsetAsync(cntk, 0, (size_t)KSPLIT * N_NODES * 4, stream);

    int ebl = (N_EDGES + 255) / 256;
    rank_kernel<<<ebl, 256, 0, stream>>>(dstp, cntk, rank, N_EDGES);
    merge_kernel<<<SCAN_NB, 256, 0, stream>>>(cntk, x, batch, cnt, bsum, dinv, g_buf,
                                              gstart, N_NODES);
    scanfill_kernel<<<SCAN_NB, 256, 0, stream>>>(cnt, bsum, rowp, N_NODES);
    fill2_kernel<<<ebl, 256, 0, stream>>>(srcp, dstp, rank, rowp, cntk, csr, N_EDGES);

    int wbl = (N_NODES + 3) / 4;          // agg9: 4 waves per block
    int gbl = (N_NODES + 63) / 64;        // layer-0 gemm: 64-node tiles
    int fbl = (N_NODES + 31) / 32;        // fused: 32-node tiles (1563 blocks)

    // layer 0: agg9 on g0 (in g_buf) -> a_buf, then 9->64 GEMM -> g_buf
    agg9_kernel<<<wbl, 256, 0, stream>>>(g_buf, csr, rowp, dinv, a_buf, N_NODES);
    gemm_tile_kernel<N_FEAT, true><<<gbl, 256, 0, stream>>>(a_buf, W0, b0, dinv,
                                                            g_buf, N_NODES);
    // layers 1..3 fused (ping-pong g_buf <-> a_buf)
    fused_kernel<true><<<fbl, 512, 0, stream>>>(g_buf, csr, rowp, dinv, W1, b1,
                                                a_buf, N_NODES);
    fused_kernel<true><<<fbl, 512, 0, stream>>>(a_buf, csr, rowp, dinv, W2, b2,
                                                g_buf, N_NODES);
    fused_kernel<false><<<fbl, 512, 0, stream>>>(g_buf, csr, rowp, dinv, W3, b3,
                                                 a_buf, N_NODES);

    pool_kernel<<<N_GRAPHS, 256, 0, stream>>>(a_buf, gstart, Wout, bout, out, N_GRAPHS);
}